// Round 8
// baseline (231.803 us; speedup 1.0000x reference)
//
#include <hip/hip_runtime.h>

#define N_NODES 100000
#define N_EDGES 3200000
#define NB_F 782                       // fine buckets: 128 dst nodes each
#define REGION 7168                    // padded per-bucket record window (16-mult)
#define TILE 8192
#define NTILES ((N_EDGES + TILE - 1) / TILE)   // 391
#define EPT (TILE / 256)               // edges per thread per tile = 32

// ---------------------------------------------------------------------------
// Workspace layout (4-byte elements):
//   gcur      NB_F*16 ints   (cursor per bucket, one per 64B line; init kb*REGION)
//   node_off  NB_F*128 ints  (absolute start of node's run in srclist)
//   node_cnt  NB_F*128 ints  (in-degree per node)
//   recs      NB_F*REGION    (packed (local_dst<<17)|src; pad slots = -1)
//   srclist   NB_F*REGION    (src per edge, node-sorted, dense per bucket)
//   p1h  16N ushorts = bf16(x @ Wl1^T)   (3.2 MB, L2-resident)
//   q1b  16N floats  = x @ Wr1^T + b1
//   p2    N floats    r2  N floats
// ---------------------------------------------------------------------------

__device__ __forceinline__ float bf2f_lo(unsigned int w) {
  return __uint_as_float(w << 16);
}
__device__ __forceinline__ float bf2f_hi(unsigned int w) {
  return __uint_as_float(w & 0xFFFF0000u);
}
__device__ __forceinline__ unsigned short f2bf(float f) {
  unsigned int b = __float_as_uint(f);
  return (unsigned short)((b + 0x7FFFu + ((b >> 16) & 1u)) >> 16);
}

__global__ __launch_bounds__(256) void k_init(int* __restrict__ gcur) {
  const int i = blockIdx.x * 256 + threadIdx.x;
  if (i < NB_F) gcur[i * 16] = i * REGION;
}

__global__ __launch_bounds__(256) void k_proj1(
    const float* __restrict__ x, const float* __restrict__ Wl1,
    const float* __restrict__ Wr1, const float* __restrict__ b1,
    unsigned short* __restrict__ p1h, float* __restrict__ q1b) {
  __shared__ float sWl[16 * 32];
  __shared__ float sWr[16 * 32];
  __shared__ float sb[16];
  const int t = threadIdx.x;
  for (int i = t; i < 512; i += 256) {
    sWl[i] = Wl1[i];
    sWr[i] = Wr1[i];
  }
  if (t < 16) sb[t] = b1[t];
  __syncthreads();

  const int n = blockIdx.x * 256 + t;
  if (n >= N_NODES) return;

  float xr[32];
  const float4* xp = (const float4*)(x + (size_t)n * 32);
#pragma unroll
  for (int j = 0; j < 8; ++j) {
    float4 v = xp[j];
    xr[4 * j + 0] = v.x;
    xr[4 * j + 1] = v.y;
    xr[4 * j + 2] = v.z;
    xr[4 * j + 3] = v.w;
  }

  float pv[16], qv[16];
#pragma unroll
  for (int hh = 0; hh < 16; ++hh) {
    float a = 0.f, b = 0.f;
#pragma unroll
    for (int i = 0; i < 32; ++i) {
      a = fmaf(xr[i], sWl[hh * 32 + i], a);
      b = fmaf(xr[i], sWr[hh * 32 + i], b);
    }
    pv[hh] = a;
    qv[hh] = b + sb[hh];
  }

  unsigned int w[8];
#pragma unroll
  for (int j = 0; j < 8; ++j)
    w[j] = (unsigned int)f2bf(pv[2 * j]) |
           ((unsigned int)f2bf(pv[2 * j + 1]) << 16);
  uint4* pp = (uint4*)(p1h + (size_t)n * 16);
  pp[0] = make_uint4(w[0], w[1], w[2], w[3]);
  pp[1] = make_uint4(w[4], w[5], w[6], w[7]);

  float4* qp = (float4*)(q1b + (size_t)n * 16);
#pragma unroll
  for (int j = 0; j < 4; ++j)
    qp[j] = make_float4(qv[4 * j], qv[4 * j + 1], qv[4 * j + 2], qv[4 * j + 3]);
}

// bucketed scatter with line-aligned single-writer runs: per (tile,bucket)
// reservation padded to 16 records (64 B). Pad slots filled with -1.
__global__ __launch_bounds__(256) void k_bscatter(const int* __restrict__ ei,
                                                  int* __restrict__ gcur,
                                                  int* __restrict__ recs) {
  __shared__ int cnt[NB_F];
  __shared__ int rbase[NB_F];
  __shared__ int cntS[NB_F];
  const int t = threadIdx.x;
  for (int i = t; i < NB_F; i += 256) cnt[i] = 0;
  __syncthreads();
  const int tb = blockIdx.x * TILE;
  int ds[EPT];
#pragma unroll
  for (int i = 0; i < EPT; ++i) {
    const int e = tb + t + i * 256;
    ds[i] = (e < N_EDGES) ? ei[N_EDGES + e] : -1;
    if (ds[i] >= 0) atomicAdd(&cnt[ds[i] >> 7], 1);
  }
  __syncthreads();
  for (int i = t; i < NB_F; i += 256) {
    const int c = cnt[i];
    cntS[i] = c;
    if (c) rbase[i] = atomicAdd(&gcur[i * 16], (c + 15) & ~15);
  }
  __syncthreads();
#pragma unroll
  for (int i = 0; i < EPT; ++i) {
    const int e = tb + t + i * 256;
    if (e < N_EDGES) {
      const int d = ds[i];
      const int s = ei[e];
      const int k = d >> 7;
      const int slot = atomicAdd(&cnt[k], -1) - 1;
      const int idx = rbase[k] + slot;
      if (idx < (k + 1) * REGION) recs[idx] = ((d & 127) << 17) | s;
    }
  }
  __syncthreads();
  for (int i = t; i < NB_F; i += 256) {
    const int c = cntS[i];
    if (c) {
      const int p = (c + 15) & ~15;
      const int b0 = rbase[i];
      const int lim = (i + 1) * REGION;
      for (int j = c; j < p; ++j) {
        const int idx = b0 + j;
        if (idx < lim) recs[idx] = -1;
      }
    }
  }
}

// per-bucket counting sort by local dst -> node-contiguous srclist (dense
// within bucket region) + node_off/node_cnt. Sentinels (-1) skipped.
__global__ __launch_bounds__(256) void k_bsort(const int* __restrict__ gcur,
                                               const int* __restrict__ recs,
                                               int* __restrict__ srclist,
                                               int* __restrict__ node_off,
                                               int* __restrict__ node_cnt) {
  __shared__ int hist[128];
  __shared__ int scn[128];
  __shared__ int cur[128];
  const int t = threadIdx.x;
  const int kb = blockIdx.x;
  const int b0 = kb * REGION;
  const int gend = gcur[kb * 16];
  if (t < 128) hist[t] = 0;
  __syncthreads();
  for (int r = b0 + t; r < gend; r += 256) {
    const int rec = recs[r];
    if (rec >= 0) atomicAdd(&hist[rec >> 17], 1);
  }
  __syncthreads();
  if (t < 128) scn[t] = hist[t];
  __syncthreads();
#pragma unroll
  for (int o = 1; o < 128; o <<= 1) {
    const int v = (t < 128 && t >= o) ? scn[t - o] : 0;
    __syncthreads();
    if (t < 128) scn[t] += v;
    __syncthreads();
  }
  if (t < 128) {
    const int ex = scn[t] - hist[t];  // exclusive scan
    cur[t] = ex;
    node_off[kb * 128 + t] = b0 + ex;
    node_cnt[kb * 128 + t] = hist[t];
  }
  __syncthreads();
  for (int r = b0 + t; r < gend; r += 256) {
    const int rec = recs[r];
    if (rec >= 0) {
      const int slot = atomicAdd(&cur[rec >> 17], 1);
      srclist[b0 + slot] = rec & 0x1FFFF;
    }
  }
}

// layer-1 aggregation: 4 lanes/node, REGISTER accumulation (no LDS atomics),
// fused relu + p2 = h@Wl2^T + r2 = h@Wr2^T. h never materialized.
__global__ __launch_bounds__(256) void k_agg1(
    const int* __restrict__ node_off, const int* __restrict__ node_cnt,
    const int* __restrict__ srclist, const unsigned short* __restrict__ p1h,
    const float* __restrict__ q1b, const float* __restrict__ Wl2,
    const float* __restrict__ Wr2, float* __restrict__ p2,
    float* __restrict__ r2) {
  __shared__ float sWl[16], sWr[16];
  const int t = threadIdx.x;
  if (t < 16) {
    sWl[t] = Wl2[t];
    sWr[t] = Wr2[t];
  }
  __syncthreads();
  const int n = blockIdx.x * 64 + (t >> 2);
  const int c = t & 3;  // lane owns channels 4c..4c+3
  if (n >= N_NODES) return;
  const int k0 = node_off[n];
  const int k = node_cnt[n];
  const int* sl = srclist + k0;
  const unsigned short* pb = p1h + c * 4;

  float a0 = 0.f, a1 = 0.f, a2 = 0.f, a3 = 0.f;
  int j = 0;
  for (; j + 4 <= k; j += 4) {
    const int s0 = sl[j], s1 = sl[j + 1], s2 = sl[j + 2], s3 = sl[j + 3];
    const uint2 w0 = *(const uint2*)(pb + (size_t)s0 * 16);
    const uint2 w1 = *(const uint2*)(pb + (size_t)s1 * 16);
    const uint2 w2 = *(const uint2*)(pb + (size_t)s2 * 16);
    const uint2 w3 = *(const uint2*)(pb + (size_t)s3 * 16);
    a0 += (bf2f_lo(w0.x) + bf2f_lo(w1.x)) + (bf2f_lo(w2.x) + bf2f_lo(w3.x));
    a1 += (bf2f_hi(w0.x) + bf2f_hi(w1.x)) + (bf2f_hi(w2.x) + bf2f_hi(w3.x));
    a2 += (bf2f_lo(w0.y) + bf2f_lo(w1.y)) + (bf2f_lo(w2.y) + bf2f_lo(w3.y));
    a3 += (bf2f_hi(w0.y) + bf2f_hi(w1.y)) + (bf2f_hi(w2.y) + bf2f_hi(w3.y));
  }
  for (; j < k; ++j) {
    const uint2 w = *(const uint2*)(pb + (size_t)sl[j] * 16);
    a0 += bf2f_lo(w.x);
    a1 += bf2f_hi(w.x);
    a2 += bf2f_lo(w.y);
    a3 += bf2f_hi(w.y);
  }

  const float di = 1.f / fmaxf((float)k, 1.f);
  const float4 q = ((const float4*)(q1b + (size_t)n * 16))[c];
  const float h0 = fmaxf(fmaf(a0, di, q.x), 0.f);
  const float h1 = fmaxf(fmaf(a1, di, q.y), 0.f);
  const float h2 = fmaxf(fmaf(a2, di, q.z), 0.f);
  const float h3 = fmaxf(fmaf(a3, di, q.w), 0.f);
  float pa = h0 * sWl[4 * c] + h1 * sWl[4 * c + 1] + h2 * sWl[4 * c + 2] +
             h3 * sWl[4 * c + 3];
  float pbv = h0 * sWr[4 * c] + h1 * sWr[4 * c + 1] + h2 * sWr[4 * c + 2] +
              h3 * sWr[4 * c + 3];
  pa += __shfl_xor(pa, 1);
  pa += __shfl_xor(pa, 2);
  pbv += __shfl_xor(pbv, 1);
  pbv += __shfl_xor(pbv, 2);
  if (c == 0) {
    p2[n] = pa;
    r2[n] = pbv;
  }
}

// layer-2 aggregation + output epilogue: 4 lanes/node, register accumulation
__global__ __launch_bounds__(256) void k_agg2out(
    const int* __restrict__ node_off, const int* __restrict__ node_cnt,
    const int* __restrict__ srclist, const float* __restrict__ p2,
    const float* __restrict__ r2, const float* __restrict__ b2,
    float* __restrict__ out) {
  const int t = threadIdx.x;
  const int n = blockIdx.x * 64 + (t >> 2);
  const int c = t & 3;
  if (n >= N_NODES) return;
  const int k0 = node_off[n];
  const int k = node_cnt[n];
  const int* sl = srclist + k0;

  float u = 0.f;
  int j = c;
  for (; j + 4 < k; j += 8) {
    const int sA = sl[j];
    const int sB = sl[j + 4];
    u += p2[sA] + p2[sB];
  }
  for (; j < k; j += 4) u += p2[sl[j]];
  u += __shfl_xor(u, 1);
  u += __shfl_xor(u, 2);
  if (c == 0) {
    const float di = 1.f / fmaxf((float)k, 1.f);
    out[n] = fmaf(u, di, r2[n] + b2[0]);
  }
}

extern "C" void kernel_launch(void* const* d_in, const int* in_sizes, int n_in,
                              void* d_out, int out_size, void* d_ws,
                              size_t ws_size, hipStream_t stream) {
  const float* x   = (const float*)d_in[0];
  const int*   ei  = (const int*)d_in[1];
  const float* Wl1 = (const float*)d_in[2];
  const float* Wr1 = (const float*)d_in[3];
  const float* b1  = (const float*)d_in[4];
  const float* Wl2 = (const float*)d_in[5];
  const float* Wr2 = (const float*)d_in[6];
  const float* b2  = (const float*)d_in[7];
  float* out = (float*)d_out;

  const size_t N = N_NODES;
  int* wi = (int*)d_ws;
  int* gcur     = wi;                                  // NB_F*16
  int* node_off = wi + NB_F * 16;                      // NB_F*128
  int* node_cnt = node_off + NB_F * 128;               // NB_F*128
  int* recs     = node_cnt + NB_F * 128;               // NB_F*REGION
  int* srclist  = recs + (size_t)NB_F * REGION;        // NB_F*REGION
  unsigned short* p1h = (unsigned short*)(srclist + (size_t)NB_F * REGION);
  float* q1b = (float*)(p1h + 16 * N);   // 16N ushorts = 8N words
  float* p2  = q1b + 16 * N;
  float* r2  = p2 + N;

  const int nodeBlocks = (N_NODES + 255) / 256;   // 391
  const int aggBlocks  = (N_NODES + 63) / 64;     // 1563
  k_init<<<(NB_F + 255) / 256, 256, 0, stream>>>(gcur);
  k_proj1<<<nodeBlocks, 256, 0, stream>>>(x, Wl1, Wr1, b1, p1h, q1b);
  k_bscatter<<<NTILES, 256, 0, stream>>>(ei, gcur, recs);
  k_bsort<<<NB_F, 256, 0, stream>>>(gcur, recs, srclist, node_off, node_cnt);
  k_agg1<<<aggBlocks, 256, 0, stream>>>(node_off, node_cnt, srclist, p1h, q1b,
                                        Wl2, Wr2, p2, r2);
  k_agg2out<<<aggBlocks, 256, 0, stream>>>(node_off, node_cnt, srclist, p2, r2,
                                           b2, out);
}

// Round 9
// 218.429 us; speedup vs baseline: 1.0612x; 1.0612x over previous
//
#include <hip/hip_runtime.h>

#define N_NODES 100000
#define N_EDGES 3200000
#define NB_F 782                       // fine buckets: 128 dst nodes each
#define RSZ 4992                       // per-bucket record window (max fill ~4500)
#define TILE 8192
#define NTILES ((N_EDGES + TILE - 1) / TILE)   // 391
#define EPT (TILE / 256)               // edges per thread per tile = 32

// ---------------------------------------------------------------------------
// Workspace layout (4-byte elements):
//   gcur      NB_F*16 ints   (cursor per bucket, one per 64B line; init kb*RSZ)
//   node_off  NB_F*128 ints  (absolute start of node's run in srclist)
//   node_cnt  NB_F*128 ints  (in-degree per node)
//   recs      NB_F*RSZ       (packed (local_dst<<17)|src; dense per bucket)
//   srclist   NB_F*RSZ       (src per edge, node-sorted, dense per bucket)
//   p1h  16N ushorts = bf16(x @ Wl1^T)   (3.2 MB, L2-resident)
//   q1b  16N floats  = x @ Wr1^T + b1
//   p2    N floats    r2  N floats
// ---------------------------------------------------------------------------

__device__ __forceinline__ float bf2f_lo(unsigned int w) {
  return __uint_as_float(w << 16);
}
__device__ __forceinline__ float bf2f_hi(unsigned int w) {
  return __uint_as_float(w & 0xFFFF0000u);
}
__device__ __forceinline__ unsigned short f2bf(float f) {
  unsigned int b = __float_as_uint(f);
  return (unsigned short)((b + 0x7FFFu + ((b >> 16) & 1u)) >> 16);
}

__global__ __launch_bounds__(256) void k_init(int* __restrict__ gcur) {
  const int i = blockIdx.x * 256 + threadIdx.x;
  if (i < NB_F) gcur[i * 16] = i * RSZ;
}

__global__ __launch_bounds__(256) void k_proj1(
    const float* __restrict__ x, const float* __restrict__ Wl1,
    const float* __restrict__ Wr1, const float* __restrict__ b1,
    unsigned short* __restrict__ p1h, float* __restrict__ q1b) {
  __shared__ float sWl[16 * 32];
  __shared__ float sWr[16 * 32];
  __shared__ float sb[16];
  const int t = threadIdx.x;
  for (int i = t; i < 512; i += 256) {
    sWl[i] = Wl1[i];
    sWr[i] = Wr1[i];
  }
  if (t < 16) sb[t] = b1[t];
  __syncthreads();

  const int n = blockIdx.x * 256 + t;
  if (n >= N_NODES) return;

  float xr[32];
  const float4* xp = (const float4*)(x + (size_t)n * 32);
#pragma unroll
  for (int j = 0; j < 8; ++j) {
    float4 v = xp[j];
    xr[4 * j + 0] = v.x;
    xr[4 * j + 1] = v.y;
    xr[4 * j + 2] = v.z;
    xr[4 * j + 3] = v.w;
  }

  float pv[16], qv[16];
#pragma unroll
  for (int hh = 0; hh < 16; ++hh) {
    float a = 0.f, b = 0.f;
#pragma unroll
    for (int i = 0; i < 32; ++i) {
      a = fmaf(xr[i], sWl[hh * 32 + i], a);
      b = fmaf(xr[i], sWr[hh * 32 + i], b);
    }
    pv[hh] = a;
    qv[hh] = b + sb[hh];
  }

  unsigned int w[8];
#pragma unroll
  for (int j = 0; j < 8; ++j)
    w[j] = (unsigned int)f2bf(pv[2 * j]) |
           ((unsigned int)f2bf(pv[2 * j + 1]) << 16);
  uint4* pp = (uint4*)(p1h + (size_t)n * 16);
  pp[0] = make_uint4(w[0], w[1], w[2], w[3]);
  pp[1] = make_uint4(w[4], w[5], w[6], w[7]);

  float4* qp = (float4*)(q1b + (size_t)n * 16);
#pragma unroll
  for (int j = 0; j < 4; ++j)
    qp[j] = make_float4(qv[4 * j], qv[4 * j + 1], qv[4 * j + 2], qv[4 * j + 3]);
}

// tile counting-sort in LDS, then POSITION-ORDER write-out: consecutive
// threads write consecutive slots of each run -> each 64B line covered by one
// wave-store (temporally adjacent) -> L2 merges, no partial-line writebacks.
__global__ __launch_bounds__(256) void k_bscatter(const int* __restrict__ ei,
                                                  int* __restrict__ gcur,
                                                  int* __restrict__ recs) {
  __shared__ int hist[1024];     // zero-padded past NB_F
  __shared__ int bstart[1024];   // exclusive scan; bstart[NB_F]=nE sentinel
  __shared__ int cur[NB_F];
  __shared__ int rbase[NB_F];
  __shared__ int stage[TILE];
  __shared__ int seg[256];
  const int t = threadIdx.x;
  for (int i = t; i < 1024; i += 256) hist[i] = 0;
  __syncthreads();

  const int tb = blockIdx.x * TILE;
  const int nE = min(TILE, N_EDGES - tb);
  int ds[EPT], ss[EPT];
#pragma unroll
  for (int i = 0; i < EPT; ++i) {
    const int e = tb + t + i * 256;
    if (e < N_EDGES) {
      ss[i] = ei[e];
      ds[i] = ei[N_EDGES + e];
      atomicAdd(&hist[ds[i] >> 7], 1);
    } else {
      ds[i] = -1;
    }
  }
  __syncthreads();

  // exclusive scan of hist[1024] with 256 threads (4 elems/thread)
  const int s0 = hist[4 * t], s1 = hist[4 * t + 1], s2 = hist[4 * t + 2],
            s3 = hist[4 * t + 3];
  const int my = s0 + s1 + s2 + s3;
  seg[t] = my;
  __syncthreads();
#pragma unroll
  for (int o = 1; o < 256; o <<= 1) {
    const int a = (t >= o) ? seg[t - o] : 0;
    __syncthreads();
    seg[t] += a;
    __syncthreads();
  }
  const int ex = seg[t] - my;
  bstart[4 * t] = ex;
  bstart[4 * t + 1] = ex + s0;
  bstart[4 * t + 2] = ex + s0 + s1;
  bstart[4 * t + 3] = ex + s0 + s1 + s2;
  __syncthreads();

  // cursors + global reservation (unpadded)
  for (int i = t; i < NB_F; i += 256) {
    cur[i] = bstart[i];
    const int c = hist[i];
    if (c) rbase[i] = atomicAdd(&gcur[i * 16], c);
  }
  __syncthreads();

  // place records into LDS stage, grouped by bucket
#pragma unroll
  for (int i = 0; i < EPT; ++i) {
    if (ds[i] >= 0) {
      const int k = ds[i] >> 7;
      const int pos = atomicAdd(&cur[k], 1);
      stage[pos] = ((ds[i] & 127) << 17) | ss[i];
    }
  }
  __syncthreads();

  // write-out in position order; bucket via binary search over bstart
  for (int pos = t; pos < nE; pos += 256) {
    int lo = 0, hi = NB_F + 1;  // bstart[NB_F] == nE (from zero padding)
    while (hi - lo > 1) {
      const int mid = (lo + hi) >> 1;
      if (bstart[mid] <= pos) lo = mid;
      else hi = mid;
    }
    const int k = lo;
    const int idx = rbase[k] + (pos - bstart[k]);
    if (idx < (k + 1) * RSZ) recs[idx] = stage[pos];
  }
}

// per-bucket counting sort by local dst; scatter into LDS then write srclist
// COALESCED (no scattered global stores).
__global__ __launch_bounds__(256) void k_bsort(const int* __restrict__ gcur,
                                               const int* __restrict__ recs,
                                               int* __restrict__ srclist,
                                               int* __restrict__ node_off,
                                               int* __restrict__ node_cnt) {
  __shared__ int hist[128];
  __shared__ int scn[128];
  __shared__ int cur[128];
  __shared__ int ssort[RSZ];
  const int t = threadIdx.x;
  const int kb = blockIdx.x;
  const int b0 = kb * RSZ;
  const int gend = gcur[kb * 16];
  if (t < 128) hist[t] = 0;
  __syncthreads();
  for (int r = b0 + t; r < gend; r += 256) atomicAdd(&hist[recs[r] >> 17], 1);
  __syncthreads();
  if (t < 128) scn[t] = hist[t];
  __syncthreads();
#pragma unroll
  for (int o = 1; o < 128; o <<= 1) {
    const int v = (t < 128 && t >= o) ? scn[t - o] : 0;
    __syncthreads();
    if (t < 128) scn[t] += v;
    __syncthreads();
  }
  if (t < 128) {
    const int ex = scn[t] - hist[t];  // exclusive scan
    cur[t] = ex;
    node_off[kb * 128 + t] = b0 + ex;
    node_cnt[kb * 128 + t] = hist[t];
  }
  __syncthreads();
  for (int r = b0 + t; r < gend; r += 256) {
    const int rec = recs[r];
    const int slot = atomicAdd(&cur[rec >> 17], 1);
    ssort[slot] = rec & 0x1FFFF;
  }
  __syncthreads();
  const int T = gend - b0;
  for (int j = t; j < T; j += 256) srclist[b0 + j] = ssort[j];
}

// layer-1 aggregation: 4 lanes/node, REGISTER accumulation (no LDS atomics),
// fused relu + p2 = h@Wl2^T + r2 = h@Wr2^T. h never materialized.
__global__ __launch_bounds__(256) void k_agg1(
    const int* __restrict__ node_off, const int* __restrict__ node_cnt,
    const int* __restrict__ srclist, const unsigned short* __restrict__ p1h,
    const float* __restrict__ q1b, const float* __restrict__ Wl2,
    const float* __restrict__ Wr2, float* __restrict__ p2,
    float* __restrict__ r2) {
  __shared__ float sWl[16], sWr[16];
  const int t = threadIdx.x;
  if (t < 16) {
    sWl[t] = Wl2[t];
    sWr[t] = Wr2[t];
  }
  __syncthreads();
  const int n = blockIdx.x * 64 + (t >> 2);
  const int c = t & 3;  // lane owns channels 4c..4c+3
  if (n >= N_NODES) return;
  const int k0 = node_off[n];
  const int k = node_cnt[n];
  const int* sl = srclist + k0;
  const unsigned short* pb = p1h + c * 4;

  float a0 = 0.f, a1 = 0.f, a2 = 0.f, a3 = 0.f;
  int j = 0;
  for (; j + 4 <= k; j += 4) {
    const int s0 = sl[j], s1 = sl[j + 1], s2 = sl[j + 2], s3 = sl[j + 3];
    const uint2 w0 = *(const uint2*)(pb + (size_t)s0 * 16);
    const uint2 w1 = *(const uint2*)(pb + (size_t)s1 * 16);
    const uint2 w2 = *(const uint2*)(pb + (size_t)s2 * 16);
    const uint2 w3 = *(const uint2*)(pb + (size_t)s3 * 16);
    a0 += (bf2f_lo(w0.x) + bf2f_lo(w1.x)) + (bf2f_lo(w2.x) + bf2f_lo(w3.x));
    a1 += (bf2f_hi(w0.x) + bf2f_hi(w1.x)) + (bf2f_hi(w2.x) + bf2f_hi(w3.x));
    a2 += (bf2f_lo(w0.y) + bf2f_lo(w1.y)) + (bf2f_lo(w2.y) + bf2f_lo(w3.y));
    a3 += (bf2f_hi(w0.y) + bf2f_hi(w1.y)) + (bf2f_hi(w2.y) + bf2f_hi(w3.y));
  }
  for (; j < k; ++j) {
    const uint2 w = *(const uint2*)(pb + (size_t)sl[j] * 16);
    a0 += bf2f_lo(w.x);
    a1 += bf2f_hi(w.x);
    a2 += bf2f_lo(w.y);
    a3 += bf2f_hi(w.y);
  }

  const float di = 1.f / fmaxf((float)k, 1.f);
  const float4 q = ((const float4*)(q1b + (size_t)n * 16))[c];
  const float h0 = fmaxf(fmaf(a0, di, q.x), 0.f);
  const float h1 = fmaxf(fmaf(a1, di, q.y), 0.f);
  const float h2 = fmaxf(fmaf(a2, di, q.z), 0.f);
  const float h3 = fmaxf(fmaf(a3, di, q.w), 0.f);
  float pa = h0 * sWl[4 * c] + h1 * sWl[4 * c + 1] + h2 * sWl[4 * c + 2] +
             h3 * sWl[4 * c + 3];
  float pbv = h0 * sWr[4 * c] + h1 * sWr[4 * c + 1] + h2 * sWr[4 * c + 2] +
              h3 * sWr[4 * c + 3];
  pa += __shfl_xor(pa, 1);
  pa += __shfl_xor(pa, 2);
  pbv += __shfl_xor(pbv, 1);
  pbv += __shfl_xor(pbv, 2);
  if (c == 0) {
    p2[n] = pa;
    r2[n] = pbv;
  }
}

// layer-2 aggregation + output epilogue: 4 lanes/node, register accumulation
__global__ __launch_bounds__(256) void k_agg2out(
    const int* __restrict__ node_off, const int* __restrict__ node_cnt,
    const int* __restrict__ srclist, const float* __restrict__ p2,
    const float* __restrict__ r2, const float* __restrict__ b2,
    float* __restrict__ out) {
  const int t = threadIdx.x;
  const int n = blockIdx.x * 64 + (t >> 2);
  const int c = t & 3;
  if (n >= N_NODES) return;
  const int k0 = node_off[n];
  const int k = node_cnt[n];
  const int* sl = srclist + k0;

  float u = 0.f;
  int j = c;
  for (; j + 4 < k; j += 8) {
    const int sA = sl[j];
    const int sB = sl[j + 4];
    u += p2[sA] + p2[sB];
  }
  for (; j < k; j += 4) u += p2[sl[j]];
  u += __shfl_xor(u, 1);
  u += __shfl_xor(u, 2);
  if (c == 0) {
    const float di = 1.f / fmaxf((float)k, 1.f);
    out[n] = fmaf(u, di, r2[n] + b2[0]);
  }
}

extern "C" void kernel_launch(void* const* d_in, const int* in_sizes, int n_in,
                              void* d_out, int out_size, void* d_ws,
                              size_t ws_size, hipStream_t stream) {
  const float* x   = (const float*)d_in[0];
  const int*   ei  = (const int*)d_in[1];
  const float* Wl1 = (const float*)d_in[2];
  const float* Wr1 = (const float*)d_in[3];
  const float* b1  = (const float*)d_in[4];
  const float* Wl2 = (const float*)d_in[5];
  const float* Wr2 = (const float*)d_in[6];
  const float* b2  = (const float*)d_in[7];
  float* out = (float*)d_out;

  const size_t N = N_NODES;
  int* wi = (int*)d_ws;
  int* gcur     = wi;                                  // NB_F*16
  int* node_off = wi + NB_F * 16;                      // NB_F*128
  int* node_cnt = node_off + NB_F * 128;               // NB_F*128
  int* recs     = node_cnt + NB_F * 128;               // NB_F*RSZ
  int* srclist  = recs + (size_t)NB_F * RSZ;           // NB_F*RSZ
  unsigned short* p1h = (unsigned short*)(srclist + (size_t)NB_F * RSZ);
  float* q1b = (float*)(p1h + 16 * N);   // 16N ushorts = 8N words
  float* p2  = q1b + 16 * N;
  float* r2  = p2 + N;

  const int nodeBlocks = (N_NODES + 255) / 256;   // 391
  const int aggBlocks  = (N_NODES + 63) / 64;     // 1563
  k_init<<<(NB_F + 255) / 256, 256, 0, stream>>>(gcur);
  k_proj1<<<nodeBlocks, 256, 0, stream>>>(x, Wl1, Wr1, b1, p1h, q1b);
  k_bscatter<<<NTILES, 256, 0, stream>>>(ei, gcur, recs);
  k_bsort<<<NB_F, 256, 0, stream>>>(gcur, recs, srclist, node_off, node_cnt);
  k_agg1<<<aggBlocks, 256, 0, stream>>>(node_off, node_cnt, srclist, p1h, q1b,
                                        Wl2, Wr2, p2, r2);
  k_agg2out<<<aggBlocks, 256, 0, stream>>>(node_off, node_cnt, srclist, p2, r2,
                                           b2, out);
}